// Round 4
// baseline (6788.091 us; speedup 1.0000x reference)
//
#include <hip/hip_runtime.h>
#include <cstdint>

constexpr int NB = 128;   // batch
constexpr int NT = 512;   // time
constexpr int ND = 64;    // input dim
constexpr int NH = 512;   // hidden
constexpr int NL = 256;   // latent

typedef _Float16 half8 __attribute__((ext_vector_type(8)));
typedef float F4 __attribute__((ext_vector_type(4)));
typedef uint32_t u32;
typedef unsigned long long u64;
typedef uint32_t u32x4 __attribute__((ext_vector_type(4)));

// ---------------- workspace layout (bytes) ----------------
constexpr size_t OFF_WFE = 0;                          // 2 MB fragment-major W_hh_e fp16
constexpr size_t OFF_WFD = (2u << 20);                 // 2 MB fragment-major W_hh_d fp16
constexpr size_t OFF_WFX = (4u << 20);                 // 256 KB fragment-major W_ih_e fp16
constexpr size_t OFF_WFO = (4u << 20) + (256u << 10);  // 64 KB fragment-major W_out fp16
constexpr size_t OFF_XF  = (4u << 20) + (320u << 10);  // 8 MB x in A-fragment layout fp16
constexpr size_t OFF_DE  = (12u << 20) + (320u << 10); // 512 KB enc ring data [8][4][16][128] u64
constexpr size_t OFF_DD  = OFF_DE + (512u << 10);      // 512 KB dec ring data
constexpr size_t OFF_TE  = OFF_DD + (512u << 10);      // 64 KB enc tags [8][128] u32 (padded)
constexpr size_t OFF_TD  = OFF_TE + (64u << 10);       // 64 KB dec tags
constexpr size_t OFF_Z   = OFF_TD + (64u << 10);       // 128 KB z fp32
constexpr size_t OFF_ZX  = OFF_Z + (128u << 10);       // 1 MB zx fp32
// total ~14.9 MB

__device__ inline float sigm(float x) {
  float e = __expf(-fabsf(x));
  float p = 1.f / (1.f + e);
  return x >= 0.f ? p : 1.f - p;
}
__device__ inline float tanh_(float x) {
  float e = __expf(-2.f * fabsf(x));
  float t = (1.f - e) / (1.f + e);
  return x >= 0.f ? t : -t;
}
__device__ inline half8 cvt8(F4 a, F4 b) {
  half8 h;
  h[0] = (_Float16)a[0]; h[1] = (_Float16)a[1]; h[2] = (_Float16)a[2]; h[3] = (_Float16)a[3];
  h[4] = (_Float16)b[0]; h[5] = (_Float16)b[1]; h[6] = (_Float16)b[2]; h[7] = (_Float16)b[3];
  return h;
}

#define PIN4(v) asm volatile("" : "+v"(v.x), "+v"(v.y), "+v"(v.z), "+v"(v.w))
#define MFMA(A, B, C) __builtin_amdgcn_mfma_f32_16x16x32_f16( \
    __builtin_bit_cast(half8, A), __builtin_bit_cast(half8, B), C, 0, 0, 0)

// ------- setup: gather weights + x into fragment-major fp16 layouts -------
__global__ __launch_bounds__(256) void setup_kernel(
    const float* __restrict__ x, const float* __restrict__ W_hh_e,
    const float* __restrict__ W_ih_e, const float* __restrict__ W_hh_d,
    const float* __restrict__ W_out,
    half8* __restrict__ WfE, half8* __restrict__ WfX, half8* __restrict__ WfD,
    half8* __restrict__ WfO, half8* __restrict__ Xf) {
  int c = blockIdx.x * 256 + threadIdx.x;
  if (c < 131072) {  // WfE
    int hc = c >> 12, g = (c >> 10) & 3, tt = (c >> 6) & 15, l = c & 63;
    int col = g * 512 + hc * 16 + (l & 15);
    int k8 = 4 * tt + (l >> 4);
    const F4* s = (const F4*)(W_hh_e + (size_t)col * 512 + k8 * 8);
    WfE[c] = cvt8(s[0], s[1]);
  } else if (c < 147456) {  // WfX
    int id = c - 131072;
    int hc = id >> 9, g = (id >> 7) & 3, tx = (id >> 6) & 1, l = id & 63;
    int col = g * 512 + hc * 16 + (l & 15);
    int k8 = 4 * tx + (l >> 4);
    const F4* s = (const F4*)(W_ih_e + (size_t)col * 64 + k8 * 8);
    WfX[id] = cvt8(s[0], s[1]);
  } else if (c < 278528) {  // WfD
    int id = c - 147456;
    int hc = id >> 12, g = (id >> 10) & 3, tt = (id >> 6) & 15, l = id & 63;
    int col = g * 512 + hc * 16 + (l & 15);
    int k8 = 4 * tt + (l >> 4);
    const F4* s = (const F4*)(W_hh_d + (size_t)col * 512 + k8 * 8);
    WfD[id] = cvt8(s[0], s[1]);
  } else if (c < 282624) {  // WfO
    int id = c - 278528;
    int dt = id >> 10, k = (id >> 6) & 15, l = id & 63;
    int d = dt * 16 + (l & 15);
    int k8 = k * 4 + (l >> 4);
    const F4* s = (const F4*)(W_out + (size_t)d * 512 + k8 * 8);
    WfO[id] = cvt8(s[0], s[1]);
  } else {  // Xf
    int id = c - 282624;
    int t = id >> 10, bi = (id >> 7) & 7, k8 = (id >> 4) & 7, row = id & 15;
    const F4* s = (const F4*)(x + ((size_t)(bi * 16 + row) * NT + t) * ND + k8 * 8);
    Xf[id] = cvt8(s[0], s[1]);
  }
}

// poll all 128 writer-wave tags of the team for >= T (per-wave, 512 B/iter)
#define POLL_TAGS(TT, T)                                                        \
  for (;;) {                                                                    \
    u32 ta = __hip_atomic_load((TT) + l, __ATOMIC_RELAXED,                      \
                               __HIP_MEMORY_SCOPE_AGENT);                       \
    u32 tb = __hip_atomic_load((TT) + 64 + l, __ATOMIC_RELAXED,                 \
                               __HIP_MEMORY_SCOPE_AGENT);                       \
    if (__all(ta >= (u32)(T) && tb >= (u32)(T))) break;                         \
  }

// stage untagged 16 KB payload of slot (T&3) into swizzled lds32
#define STAGE_DATA(DT, T)                                                       \
  {                                                                             \
    const u64* dp = (DT) + (size_t)((T) & 3) * 2048 + srow * 128 + scb * 8;     \
    u64 v[8];                                                                   \
    _Pragma("unroll")                                                           \
    for (int j = 0; j < 8; j++)                                                 \
      v[j] = __hip_atomic_load(dp + j, __ATOMIC_RELAXED,                        \
                               __HIP_MEMORY_SCOPE_AGENT);                       \
    _Pragma("unroll")                                                           \
    for (int j = 0; j < 8; j++) {                                               \
      int cc = scb * 4 + (j >> 1);                                              \
      *(u64*)&lds32[srow * 256 + ((cc ^ (srow & 7)) << 2) + (j & 1) * 2] = v[j];\
    }                                                                           \
  }

// publish this wave's 4 h-rows (shuffle-pack) + release + tag
#define PUBLISH(DT, TT, HV, T)                                                  \
  {                                                                             \
    u32 self = (u32)__builtin_bit_cast(unsigned short, (_Float16)(HV));         \
    u32 part = (u32)__shfl_xor((int)self, 1);                                   \
    u32 p32 = (l & 1) ? ((self << 16) | part) : ((part << 16) | self);          \
    u32 q = (u32)__shfl_xor((int)p32, 2);                                       \
    u64 p64 = (l & 2) ? (((u64)p32 << 32) | q) : (((u64)q << 32) | p32);        \
    if ((l & 3) == 0)                                                           \
      __hip_atomic_store((DT) + (size_t)(((T) + 1) & 3) * 2048 +                \
                             (size_t)row * 128 + w * 4 + ((l >> 2) & 3),        \
                         p64, __ATOMIC_RELAXED, __HIP_MEMORY_SCOPE_AGENT);      \
    asm volatile("s_waitcnt vmcnt(0)" ::: "memory");                            \
    if (l == 0)                                                                 \
      __hip_atomic_store((TT) + w * 4 + g, (u32)((T) + 1), __ATOMIC_RELAXED,    \
                         __HIP_MEMORY_SCOPE_AGENT);                             \
  }

// ------------------------- persistent encoder -------------------------
__global__ __launch_bounds__(256, 1) void enc_persist(
    const uint4* __restrict__ Wf, const uint4* __restrict__ Wfx,
    const uint4* __restrict__ Xf, u64* __restrict__ Data, u32* __restrict__ Tag,
    const float* __restrict__ b_e, const int* __restrict__ lengths) {
  const int tid = threadIdx.x;
  const int l = tid & 63, g = tid >> 6;
  const int bi = (int)blockIdx.x & 7, w = (int)blockIdx.x >> 3;
  __shared__ u32 lds32[4096];
  __shared__ float gl[4][16][17];

  uint4 wb[16];
#pragma unroll
  for (int k = 0; k < 16; k++) wb[k] = Wf[(size_t)w * 4096 + (g * 16 + k) * 64 + l];
  uint4 wx0 = Wfx[(size_t)w * 512 + (g * 2 + 0) * 64 + l];
  uint4 wx1 = Wfx[(size_t)w * 512 + (g * 2 + 1) * 64 + l];

  const int row = tid >> 4, col = tid & 15;
  const int len = lengths[bi * 16 + row];
  const float be0 = b_e[w * 16 + col], be1 = b_e[512 + w * 16 + col];
  const float be2 = b_e[1024 + w * 16 + col], be3 = b_e[1536 + w * 16 + col];
  float cst = 0.f, hreg = 0.f;
  const int srow = tid >> 4, scb = tid & 15;
  u64* DT = Data + (size_t)bi * 8192;
  u32* TT = Tag + bi * 128;
  const int ar = l & 15, swz = ar & 7, r0v = (l >> 4) * 4;

  for (int t = 0; t < NT; t++) {
#pragma unroll
    for (int k = 0; k < 16; k++) PIN4(wb[k]);
    PIN4(wx0); PIN4(wx1);
    uint4 xa0 = Xf[((size_t)t * 8 + bi) * 128 + l];
    uint4 xa1 = Xf[((size_t)t * 8 + bi) * 128 + 64 + l];
    if (t > 0) {
      POLL_TAGS(TT, t);
      STAGE_DATA(DT, t);
      __syncthreads();
    }
    F4 acc0 = {0.f, 0.f, 0.f, 0.f}, acc1 = {0.f, 0.f, 0.f, 0.f};
    acc0 = MFMA(xa0, wx0, acc0);
    acc1 = MFMA(xa1, wx1, acc1);
    if (t > 0) {
#pragma unroll
      for (int k = 0; k < 16; k += 2) {
        u32x4 a0 = *(u32x4*)&lds32[ar * 256 + (((4 * k + (l >> 4)) ^ swz) << 2)];
        u32x4 a1 = *(u32x4*)&lds32[ar * 256 + (((4 * (k + 1) + (l >> 4)) ^ swz) << 2)];
        acc0 = MFMA(a0, wb[k], acc0);
        acc1 = MFMA(a1, wb[k + 1], acc1);
      }
    }
    F4 acc = acc0 + acc1;
#pragma unroll
    for (int r = 0; r < 4; r++) gl[g][r0v + r][ar] = acc[r];
    __syncthreads();

    float hv;
    if (t < len) {
      float gi = gl[0][row][col] + be0;
      float gf = gl[1][row][col] + be1;
      float gg = gl[2][row][col] + be2;
      float go = gl[3][row][col] + be3;
      float i = sigm(gi), f = sigm(gf), gz = tanh_(gg), o = sigm(go);
      cst = f * cst + i * gz;
      hv = o * tanh_(cst);
    } else {
      hv = hreg;
    }
    hreg = hv;
    PUBLISH(DT, TT, hv, t);
  }
}

// ------------------------- z / zx -------------------------
__global__ __launch_bounds__(256) void z_kernel(const u32* __restrict__ DataE,
                                                const float* __restrict__ W_lat,
                                                const float* __restrict__ b_lat,
                                                float* __restrict__ Z) {
  int b = blockIdx.x, lc = threadIdx.x;
  int bi = b >> 4, row = b & 15;
  const u32* hp = DataE + (size_t)bi * 16384 + (size_t)row * 256;  // slot 0 (512&3)
  float acc = 0.f;
  for (int j = 0; j < 256; j++) {
    u32 lo = hp[j];
    float h0 = (float)__builtin_bit_cast(_Float16, (unsigned short)(lo & 0xFFFF));
    float h1 = (float)__builtin_bit_cast(_Float16, (unsigned short)(lo >> 16));
    acc += h0 * W_lat[(size_t)lc * 512 + 2 * j] + h1 * W_lat[(size_t)lc * 512 + 2 * j + 1];
  }
  Z[(size_t)b * 256 + lc] = acc + b_lat[lc];
}

__global__ __launch_bounds__(256) void zx_kernel(const float* __restrict__ Z,
                                                 const float* __restrict__ W_ihd,
                                                 const float* __restrict__ b_d,
                                                 float* __restrict__ ZX) {
  int o = blockIdx.x * 256 + threadIdx.x;
  int b = o >> 11, gc = o & 2047;
  const F4* zp = (const F4*)(Z + (size_t)b * 256);
  const F4* wp = (const F4*)(W_ihd + (size_t)gc * 256);
  float acc = 0.f;
  for (int k4 = 0; k4 < 64; k4++) {
    F4 z = zp[k4], wv = wp[k4];
    acc += z[0] * wv[0] + z[1] * wv[1] + z[2] * wv[2] + z[3] * wv[3];
  }
  ZX[o] = acc + b_d[gc];
}

// ------------------------- persistent decoder -------------------------
#define OUT_PROJ(TCUR)                                                           \
  {                                                                              \
    bool ma = ((TCUR) < lenA);                                                   \
    F4 oa0 = {0.f, 0.f, 0.f, 0.f}, oa1 = {0.f, 0.f, 0.f, 0.f};                   \
    u32x4 zer = {0u, 0u, 0u, 0u};                                                \
    _Pragma("unroll")                                                            \
    for (int k = 0; k < 16; k += 2) {                                            \
      u32x4 a0 = ma ? *(u32x4*)&lds32[ar * 256 + (((4 * k + (l >> 4)) ^ swz) << 2)] : zer; \
      u32x4 a1 = ma ? *(u32x4*)&lds32[ar * 256 + (((4 * (k + 1) + (l >> 4)) ^ swz) << 2)] : zer; \
      oa0 = MFMA(a0, wo[k], oa0);                                                \
      oa1 = MFMA(a1, wo[k + 1], oa1);                                            \
    }                                                                            \
    F4 oa = oa0 + oa1;                                                           \
    _Pragma("unroll")                                                            \
    for (int r = 0; r < 4; r++)                                                  \
      out[((size_t)(bi * 16 + r0v + r) * NT + (TCUR)) * 64 + g * 16 + (l & 15)] = oa[r] + bo; \
  }

__global__ __launch_bounds__(256, 1) void dec_persist(
    const uint4* __restrict__ Wf, const uint4* __restrict__ WfO,
    u64* __restrict__ Data, u32* __restrict__ Tag, const float* __restrict__ ZX,
    const float* __restrict__ b_out, float* __restrict__ out,
    const int* __restrict__ lengths) {
  const int tid = threadIdx.x;
  const int l = tid & 63, g = tid >> 6;
  const int bi = (int)blockIdx.x & 7, w = (int)blockIdx.x >> 3;
  __shared__ u32 lds32[4096];
  __shared__ float gl[4][16][17];

  uint4 wb[16], wo[16];
#pragma unroll
  for (int k = 0; k < 16; k++) {
    wb[k] = Wf[(size_t)w * 4096 + (g * 16 + k) * 64 + l];
    wo[k] = WfO[(size_t)g * 1024 + k * 64 + l];
  }

  const int row = tid >> 4, col = tid & 15;
  const int b = bi * 16 + row;
  const int len = lengths[b];
  const int lenA = lengths[bi * 16 + (l & 15)];
  const float bo = b_out[g * 16 + (l & 15)];
  const float zr0 = ZX[(size_t)b * 2048 + w * 16 + col];
  const float zr1 = ZX[(size_t)b * 2048 + 512 + w * 16 + col];
  const float zr2 = ZX[(size_t)b * 2048 + 1024 + w * 16 + col];
  const float zr3 = ZX[(size_t)b * 2048 + 1536 + w * 16 + col];
  float cst = 0.f, hreg = 0.f;
  const int srow = tid >> 4, scb = tid & 15;
  u64* DT = Data + (size_t)bi * 8192;
  u32* TT = Tag + bi * 128;
  const int ar = l & 15, swz = ar & 7, r0v = (l >> 4) * 4;

  for (int t = 0; t < NT; t++) {
#pragma unroll
    for (int k = 0; k < 16; k++) { PIN4(wb[k]); PIN4(wo[k]); }
    if (t > 0) {
      POLL_TAGS(TT, t);
      STAGE_DATA(DT, t);
      __syncthreads();
    }
    F4 acc0 = {0.f, 0.f, 0.f, 0.f}, acc1 = {0.f, 0.f, 0.f, 0.f};
    if (t > 0) {
#pragma unroll
      for (int k = 0; k < 16; k += 2) {
        u32x4 a0 = *(u32x4*)&lds32[ar * 256 + (((4 * k + (l >> 4)) ^ swz) << 2)];
        u32x4 a1 = *(u32x4*)&lds32[ar * 256 + (((4 * (k + 1) + (l >> 4)) ^ swz) << 2)];
        acc0 = MFMA(a0, wb[k], acc0);
        acc1 = MFMA(a1, wb[k + 1], acc1);
      }
    }
    F4 acc = acc0 + acc1;
#pragma unroll
    for (int r = 0; r < 4; r++) gl[g][r0v + r][ar] = acc[r];
    __syncthreads();

    float hv;
    if (t < len) {
      float gi = gl[0][row][col] + zr0;
      float gf = gl[1][row][col] + zr1;
      float gg = gl[2][row][col] + zr2;
      float go = gl[3][row][col] + zr3;
      float i = sigm(gi), f = sigm(gf), gz = tanh_(gg), o = sigm(go);
      cst = f * cst + i * gz;
      hv = o * tanh_(cst);
    } else {
      hv = hreg;
    }
    hreg = hv;
    PUBLISH(DT, TT, hv, t);

    // fused output projection for time t-1 from lds32 (h^t), off critical path
    if (t > 0 && w == ((t - 1) & 31)) OUT_PROJ(t - 1);
    __syncthreads();  // protect lds32 from next step's stage overwrite
  }

  // tail: out column t = NT-1 from final h (slot 0, tag NT)
  if (w == 31) {
    POLL_TAGS(TT, NT);
    STAGE_DATA(DT, NT);
    __syncthreads();
    OUT_PROJ(NT - 1);
  }
}

// ------------------------- host -------------------------
extern "C" void kernel_launch(void* const* d_in, const int* in_sizes, int n_in,
                              void* d_out, int out_size, void* d_ws, size_t ws_size,
                              hipStream_t stream) {
  const float* x      = (const float*)d_in[0];
  const int* lengths  = (const int*)d_in[1];
  const float* W_ih_e = (const float*)d_in[2];
  const float* W_hh_e = (const float*)d_in[3];
  const float* b_e    = (const float*)d_in[4];
  const float* W_lat  = (const float*)d_in[5];
  const float* b_lat  = (const float*)d_in[6];
  const float* W_ih_d = (const float*)d_in[7];
  const float* W_hh_d = (const float*)d_in[8];
  const float* b_d    = (const float*)d_in[9];
  const float* W_out  = (const float*)d_in[10];
  const float* b_out  = (const float*)d_in[11];
  float* out = (float*)d_out;
  char* ws = (char*)d_ws;

  half8* WfE = (half8*)(ws + OFF_WFE);
  half8* WfD = (half8*)(ws + OFF_WFD);
  half8* WfX = (half8*)(ws + OFF_WFX);
  half8* WfO = (half8*)(ws + OFF_WFO);
  half8* Xf  = (half8*)(ws + OFF_XF);
  u64* DataE = (u64*)(ws + OFF_DE);
  u64* DataD = (u64*)(ws + OFF_DD);
  u32* TagE  = (u32*)(ws + OFF_TE);
  u32* TagD  = (u32*)(ws + OFF_TD);
  float* Z  = (float*)(ws + OFF_Z);
  float* ZX = (float*)(ws + OFF_ZX);

  hipMemsetAsync(TagE, 0, 128u << 10, stream);  // TagE + TagD (contiguous)
  setup_kernel<<<3152, 256, 0, stream>>>(x, W_hh_e, W_ih_e, W_hh_d, W_out,
                                         WfE, WfX, WfD, WfO, Xf);

  enc_persist<<<256, 256, 0, stream>>>((const uint4*)WfE, (const uint4*)WfX,
                                       (const uint4*)Xf, DataE, TagE, b_e, lengths);
  z_kernel<<<128, 256, 0, stream>>>((const u32*)DataE, W_lat, b_lat, Z);
  zx_kernel<<<1024, 256, 0, stream>>>(Z, W_ih_d, b_d, ZX);
  dec_persist<<<256, 256, 0, stream>>>((const uint4*)WfD, (const uint4*)WfO,
                                       DataD, TagD, ZX, b_out, out, lengths);
}

// Round 5
// 3703.550 us; speedup vs baseline: 1.8329x; 1.8329x over previous
//
#include <hip/hip_runtime.h>
#include <cstdint>

constexpr int NB = 128;   // batch
constexpr int NT = 512;   // time
constexpr int ND = 64;    // input dim
constexpr int NH = 512;   // hidden
constexpr int NL = 256;   // latent

typedef _Float16 half8 __attribute__((ext_vector_type(8)));
typedef float F4 __attribute__((ext_vector_type(4)));
typedef uint32_t u32;
typedef unsigned long long u64;
typedef uint32_t u32x4 __attribute__((ext_vector_type(4)));

// ---------------- workspace layout (bytes) ----------------
constexpr size_t OFF_WFE = 0;                          // 2 MB fragment-major W_hh_e fp16
constexpr size_t OFF_WFD = (2u << 20);                 // 2 MB fragment-major W_hh_d fp16
constexpr size_t OFF_WFX = (4u << 20);                 // 256 KB fragment-major W_ih_e fp16
constexpr size_t OFF_WFO = (4u << 20) + (256u << 10);  // 64 KB fragment-major W_out fp16
constexpr size_t OFF_XF  = (4u << 20) + (320u << 10);  // 8 MB x in A-fragment layout fp16
constexpr size_t OFF_DE  = (12u << 20) + (320u << 10); // 512 KB enc ring data [8][4][16][128] u64
constexpr size_t OFF_DD  = OFF_DE + (512u << 10);      // 512 KB dec ring data
constexpr size_t OFF_TE  = OFF_DD + (512u << 10);      // 64 KB enc tags [8 teams][8 wg x 16-stride] u32
constexpr size_t OFF_TD  = OFF_TE + (64u << 10);       // 64 KB dec tags
constexpr size_t OFF_Z   = OFF_TD + (64u << 10);       // 128 KB z fp32
constexpr size_t OFF_ZX  = OFF_Z + (128u << 10);       // 1 MB zx fp32

__device__ inline float sigm(float x) {
  float e = __expf(-fabsf(x));
  float p = 1.f / (1.f + e);
  return x >= 0.f ? p : 1.f - p;
}
__device__ inline float tanh_(float x) {
  float e = __expf(-2.f * fabsf(x));
  float t = (1.f - e) / (1.f + e);
  return x >= 0.f ? t : -t;
}
__device__ inline half8 cvt8(F4 a, F4 b) {
  half8 h;
  h[0] = (_Float16)a[0]; h[1] = (_Float16)a[1]; h[2] = (_Float16)a[2]; h[3] = (_Float16)a[3];
  h[4] = (_Float16)b[0]; h[5] = (_Float16)b[1]; h[6] = (_Float16)b[2]; h[7] = (_Float16)b[3];
  return h;
}

#define PIN4(v) asm volatile("" : "+v"(v.x), "+v"(v.y), "+v"(v.z), "+v"(v.w))
#define MFMA(A, B, C) __builtin_amdgcn_mfma_f32_16x16x32_f16( \
    __builtin_bit_cast(half8, A), __builtin_bit_cast(half8, B), C, 0, 0, 0)

// ------- setup: gather weights + x into fragment-major fp16 layouts -------
// WfE2/WfD2 chunk idx = ((j*16 + t)*16 + tk)*64 + l
//   col = (t>>2)*512 + j*64 + (t&3)*16 + (l&15), k8 = tk*4 + (l>>4)
// WfX2 chunk idx = ((j*16 + t)*2 + tx)*64 + l, k8 = tx*4 + (l>>4)
// WfO  chunk idx = (dt*16 + k)*64 + l : d = dt*16+(l&15), k8 = k*4+(l>>4)
// Xf   chunk idx = (t*8 + bi)*128 + k8*16 + row
__global__ __launch_bounds__(256) void setup_kernel(
    const float* __restrict__ x, const float* __restrict__ W_hh_e,
    const float* __restrict__ W_ih_e, const float* __restrict__ W_hh_d,
    const float* __restrict__ W_out,
    half8* __restrict__ WfE, half8* __restrict__ WfX, half8* __restrict__ WfD,
    half8* __restrict__ WfO, half8* __restrict__ Xf) {
  int c = blockIdx.x * 256 + threadIdx.x;
  if (c < 131072) {  // WfE2
    int l = c & 63, tk = (c >> 6) & 15, t = (c >> 10) & 15, j = c >> 14;
    int col = (t >> 2) * 512 + j * 64 + (t & 3) * 16 + (l & 15);
    int k8 = tk * 4 + (l >> 4);
    const F4* s = (const F4*)(W_hh_e + (size_t)col * 512 + k8 * 8);
    WfE[c] = cvt8(s[0], s[1]);
  } else if (c < 147456) {  // WfX2
    int id = c - 131072;
    int l = id & 63, tx = (id >> 6) & 1, t = (id >> 7) & 15, j = id >> 11;
    int col = (t >> 2) * 512 + j * 64 + (t & 3) * 16 + (l & 15);
    int k8 = tx * 4 + (l >> 4);
    const F4* s = (const F4*)(W_ih_e + (size_t)col * 64 + k8 * 8);
    WfX[id] = cvt8(s[0], s[1]);
  } else if (c < 278528) {  // WfD2
    int id = c - 147456;
    int l = id & 63, tk = (id >> 6) & 15, t = (id >> 10) & 15, j = id >> 14;
    int col = (t >> 2) * 512 + j * 64 + (t & 3) * 16 + (l & 15);
    int k8 = tk * 4 + (l >> 4);
    const F4* s = (const F4*)(W_hh_d + (size_t)col * 512 + k8 * 8);
    WfD[id] = cvt8(s[0], s[1]);
  } else if (c < 282624) {  // WfO
    int id = c - 278528;
    int dt = id >> 10, k = (id >> 6) & 15, l = id & 63;
    int d = dt * 16 + (l & 15);
    int k8 = k * 4 + (l >> 4);
    const F4* s = (const F4*)(W_out + (size_t)d * 512 + k8 * 8);
    WfO[id] = cvt8(s[0], s[1]);
  } else {  // Xf
    int id = c - 282624;
    int t = id >> 10, bi = (id >> 7) & 7, k8 = (id >> 4) & 7, row = id & 15;
    const F4* s = (const F4*)(x + ((size_t)(bi * 16 + row) * NT + t) * ND + k8 * 8);
    Xf[id] = cvt8(s[0], s[1]);
  }
}

// wave0-only poll of the team's 8 per-WG tags (own 64B lines) with backoff
#define POLL_TAGS(TT, T)                                                        \
  {                                                                             \
    u32 tg = 0;                                                                 \
    for (;;) {                                                                  \
      if (l < 8)                                                                \
        tg = __hip_atomic_load((TT) + l * 16, __ATOMIC_RELAXED,                 \
                               __HIP_MEMORY_SCOPE_AGENT);                       \
      if (__all(l < 8 ? (tg >= (u32)(T)) : true)) break;                        \
      __builtin_amdgcn_s_sleep(2);                                              \
    }                                                                           \
  }

// stage slot (T&3): thread (row=tid>>5, c2=tid&31) loads 4 u64, writes 2x16B swizzled
#define STAGE_DATA(DT, T)                                                       \
  {                                                                             \
    const u64* dp = (DT) + (size_t)((T) & 3) * 2048 + row * 128 + c2 * 4;       \
    u64 v0 = __hip_atomic_load(dp + 0, __ATOMIC_RELAXED, __HIP_MEMORY_SCOPE_AGENT); \
    u64 v1 = __hip_atomic_load(dp + 1, __ATOMIC_RELAXED, __HIP_MEMORY_SCOPE_AGENT); \
    u64 v2 = __hip_atomic_load(dp + 2, __ATOMIC_RELAXED, __HIP_MEMORY_SCOPE_AGENT); \
    u64 v3 = __hip_atomic_load(dp + 3, __ATOMIC_RELAXED, __HIP_MEMORY_SCOPE_AGENT); \
    u32x4 pa = {(u32)v0, (u32)(v0 >> 32), (u32)v1, (u32)(v1 >> 32)};            \
    u32x4 pb = {(u32)v2, (u32)(v2 >> 32), (u32)v3, (u32)(v3 >> 32)};            \
    lds128[row * 64 + ((2 * c2) ^ (row & 7))] = pa;                             \
    lds128[row * 64 + ((2 * c2 + 1) ^ (row & 7))] = pb;                         \
  }

// publish: pack 2 cells -> u32, pair via shfl -> u64 store, ack, barrier, tag
#define PUBLISH(DT, TT, H0, H1, T)                                              \
  {                                                                             \
    u32 own = (u32)__builtin_bit_cast(unsigned short, (_Float16)(H0)) |         \
              ((u32)__builtin_bit_cast(unsigned short, (_Float16)(H1)) << 16);  \
    u32 part = (u32)__shfl_xor((int)own, 1);                                    \
    if (!(tid & 1)) {                                                           \
      u64 p64 = ((u64)part << 32) | own;                                        \
      __hip_atomic_store((DT) + (size_t)(((T) + 1) & 3) * 2048 + row * 128 +    \
                             j * 16 + (c2 >> 1),                                \
                         p64, __ATOMIC_RELAXED, __HIP_MEMORY_SCOPE_AGENT);      \
    }                                                                           \
    asm volatile("s_waitcnt vmcnt(0)" ::: "memory");                            \
    __syncthreads();                                                            \
    if (tid == 0)                                                               \
      __hip_atomic_store((TT) + j * 16, (u32)((T) + 1), __ATOMIC_RELAXED,       \
                         __HIP_MEMORY_SCOPE_AGENT);                             \
  }

// ------------------------- persistent encoder -------------------------
// 64 WGs x 512 thr: team bi = blockIdx&7, WG j = blockIdx>>3 owns hcols [j*64, j*64+64)
__global__ __launch_bounds__(512, 1) void enc_persist(
    const uint4* __restrict__ Wf, const uint4* __restrict__ Wfx,
    const uint4* __restrict__ Xf, u64* __restrict__ Data, u32* __restrict__ Tag,
    const float* __restrict__ b_e, const int* __restrict__ lengths) {
  const int tid = threadIdx.x;
  const int l = tid & 63, v = tid >> 6;
  const int bi = (int)blockIdx.x & 7, j = (int)blockIdx.x >> 3;
  __shared__ u32x4 lds128[1024];   // 16 KB staged h (swizzled, 16B units)
  __shared__ float gl[4][16][68];  // 17.4 KB gate tile

  const int t0 = 2 * v, t1 = 2 * v + 1;
  uint4 wb[16], wb2[16], wx0, wx1, wx20, wx21;
#pragma unroll
  for (int k = 0; k < 16; k++) {
    wb[k]  = Wf[(size_t)((j * 16 + t0) * 16 + k) * 64 + l];
    wb2[k] = Wf[(size_t)((j * 16 + t1) * 16 + k) * 64 + l];
  }
  wx0  = Wfx[(size_t)((j * 16 + t0) * 2 + 0) * 64 + l];
  wx1  = Wfx[(size_t)((j * 16 + t0) * 2 + 1) * 64 + l];
  wx20 = Wfx[(size_t)((j * 16 + t1) * 2 + 0) * 64 + l];
  wx21 = Wfx[(size_t)((j * 16 + t1) * 2 + 1) * 64 + l];

  const int row = tid >> 5, c2 = tid & 31;  // cell: 2 cols (local 2c2, 2c2+1)
  const int col0 = j * 64 + 2 * c2;
  const int len = lengths[bi * 16 + row];
  float be[4][2];
#pragma unroll
  for (int g = 0; g < 4; g++) {
    be[g][0] = b_e[g * 512 + col0];
    be[g][1] = b_e[g * 512 + col0 + 1];
  }
  float cst0 = 0.f, cst1 = 0.f, hr0 = 0.f, hr1 = 0.f;

  const int ar = l & 15, q = l >> 4, swz = ar & 7, r0v = q * 4;
  const int gg = v >> 1, cb0 = (t0 & 3) * 16;
  u64* DT = Data + (size_t)bi * 8192;
  u32* TT = Tag + bi * 128;

  for (int t = 0; t < NT; t++) {
#pragma unroll
    for (int k = 0; k < 16; k++) { PIN4(wb[k]); PIN4(wb2[k]); }
    PIN4(wx0); PIN4(wx1); PIN4(wx20); PIN4(wx21);
    uint4 xa0 = Xf[((size_t)t * 8 + bi) * 128 + l];
    uint4 xa1 = Xf[((size_t)t * 8 + bi) * 128 + 64 + l];
    if (t > 0) {
      if (v == 0) POLL_TAGS(TT, t);
      __syncthreads();
      STAGE_DATA(DT, t);
      __syncthreads();
    }
    F4 acc0 = {0.f, 0.f, 0.f, 0.f}, acc1 = {0.f, 0.f, 0.f, 0.f};
    acc0 = MFMA(xa0, wx0, acc0);  acc0 = MFMA(xa1, wx1, acc0);
    acc1 = MFMA(xa0, wx20, acc1); acc1 = MFMA(xa1, wx21, acc1);
    if (t > 0) {
#pragma unroll
      for (int k = 0; k < 16; k++) {
        u32x4 af = lds128[ar * 64 + ((4 * k + q) ^ swz)];
        acc0 = MFMA(af, wb[k], acc0);
        acc1 = MFMA(af, wb2[k], acc1);
      }
    }
#pragma unroll
    for (int r = 0; r < 4; r++) {
      gl[gg][r0v + r][cb0 + ar] = acc0[r];
      gl[gg][r0v + r][cb0 + 16 + ar] = acc1[r];
    }
    __syncthreads();

    float hv0, hv1;
    if (t < len) {
      int cc = 2 * c2;
      float i0 = sigm(gl[0][row][cc] + be[0][0]);
      float f0 = sigm(gl[1][row][cc] + be[1][0]);
      float g0 = tanh_(gl[2][row][cc] + be[2][0]);
      float o0 = sigm(gl[3][row][cc] + be[3][0]);
      cst0 = f0 * cst0 + i0 * g0;
      hv0 = o0 * tanh_(cst0);
      float i1 = sigm(gl[0][row][cc + 1] + be[0][1]);
      float f1 = sigm(gl[1][row][cc + 1] + be[1][1]);
      float g1 = tanh_(gl[2][row][cc + 1] + be[2][1]);
      float o1 = sigm(gl[3][row][cc + 1] + be[3][1]);
      cst1 = f1 * cst1 + i1 * g1;
      hv1 = o1 * tanh_(cst1);
    } else {
      hv0 = hr0; hv1 = hr1;
    }
    hr0 = hv0; hr1 = hv1;
    PUBLISH(DT, TT, hv0, hv1, t);
  }
}

// ------------------------- z / zx -------------------------
__global__ __launch_bounds__(256) void z_kernel(const u32* __restrict__ DataE,
                                                const float* __restrict__ W_lat,
                                                const float* __restrict__ b_lat,
                                                float* __restrict__ Z) {
  int b = blockIdx.x, lc = threadIdx.x;
  int bi = b >> 4, row = b & 15;
  const u32* hp = DataE + (size_t)bi * 16384 + (size_t)row * 256;  // slot 0
  float acc = 0.f;
  for (int jj = 0; jj < 256; jj++) {
    u32 lo = hp[jj];
    float h0 = (float)__builtin_bit_cast(_Float16, (unsigned short)(lo & 0xFFFF));
    float h1 = (float)__builtin_bit_cast(_Float16, (unsigned short)(lo >> 16));
    acc += h0 * W_lat[(size_t)lc * 512 + 2 * jj] + h1 * W_lat[(size_t)lc * 512 + 2 * jj + 1];
  }
  Z[(size_t)b * 256 + lc] = acc + b_lat[lc];
}

__global__ __launch_bounds__(256) void zx_kernel(const float* __restrict__ Z,
                                                 const float* __restrict__ W_ihd,
                                                 const float* __restrict__ b_d,
                                                 float* __restrict__ ZX) {
  int o = blockIdx.x * 256 + threadIdx.x;
  int b = o >> 11, gc = o & 2047;
  const F4* zp = (const F4*)(Z + (size_t)b * 256);
  const F4* wp = (const F4*)(W_ihd + (size_t)gc * 256);
  float acc = 0.f;
  for (int k4 = 0; k4 < 64; k4++) {
    F4 z = zp[k4], wv = wp[k4];
    acc += z[0] * wv[0] + z[1] * wv[1] + z[2] * wv[2] + z[3] * wv[3];
  }
  ZX[o] = acc + b_d[gc];
}

// ------------------------- persistent decoder -------------------------
// out-proj: WG j owns dt = j&3, step-parity j>>2; one rotating wave does 16 MFMAs
#define OUT_PROJ(TC)                                                            \
  {                                                                             \
    bool ma = ((TC) < lenA);                                                    \
    F4 oa = {0.f, 0.f, 0.f, 0.f};                                               \
    u32x4 zer = {0u, 0u, 0u, 0u};                                               \
    _Pragma("unroll")                                                           \
    for (int tk = 0; tk < 16; tk++) {                                           \
      u32x4 af = ma ? lds128[ar * 64 + ((4 * tk + q) ^ swz)] : zer;             \
      uint4 ow = wo_lds[tk * 64 + l];                                           \
      oa = MFMA(af, ow, oa);                                                    \
    }                                                                           \
    _Pragma("unroll")                                                           \
    for (int r = 0; r < 4; r++)                                                 \
      out[((size_t)(bi * 16 + r0v + r) * NT + (TC)) * 64 + (j & 3) * 16 + ar] = \
          oa[r] + bo;                                                           \
  }

__global__ __launch_bounds__(512, 1) void dec_persist(
    const uint4* __restrict__ Wf, const uint4* __restrict__ WfO,
    u64* __restrict__ Data, u32* __restrict__ Tag, const float* __restrict__ ZX,
    const float* __restrict__ b_out, float* __restrict__ out,
    const int* __restrict__ lengths) {
  const int tid = threadIdx.x;
  const int l = tid & 63, v = tid >> 6;
  const int bi = (int)blockIdx.x & 7, j = (int)blockIdx.x >> 3;
  __shared__ u32x4 lds128[1024];   // 16 KB
  __shared__ float gl[4][16][68];  // 17.4 KB
  __shared__ uint4 wo_lds[1024];   // 16 KB W_out slice for dt = j&3

  const int t0 = 2 * v, t1 = 2 * v + 1;
  uint4 wb[16], wb2[16];
#pragma unroll
  for (int k = 0; k < 16; k++) {
    wb[k]  = Wf[(size_t)((j * 16 + t0) * 16 + k) * 64 + l];
    wb2[k] = Wf[(size_t)((j * 16 + t1) * 16 + k) * 64 + l];
  }
  for (int i = tid; i < 1024; i += 512) wo_lds[i] = WfO[(size_t)(j & 3) * 1024 + i];

  const int row = tid >> 5, c2 = tid & 31;
  const int col0 = j * 64 + 2 * c2;
  const int b = bi * 16 + row;
  const int len = lengths[b];
  float zr[4][2];
#pragma unroll
  for (int g = 0; g < 4; g++) {
    zr[g][0] = ZX[(size_t)b * 2048 + g * 512 + col0];
    zr[g][1] = ZX[(size_t)b * 2048 + g * 512 + col0 + 1];
  }
  const int ar = l & 15, q = l >> 4, swz = ar & 7, r0v = q * 4;
  const int gg = v >> 1, cb0 = (t0 & 3) * 16;
  const int lenA = lengths[bi * 16 + ar];
  const float bo = b_out[(j & 3) * 16 + ar];
  float cst0 = 0.f, cst1 = 0.f, hr0 = 0.f, hr1 = 0.f;
  u64* DT = Data + (size_t)bi * 8192;
  u32* TT = Tag + bi * 128;

  for (int t = 0; t < NT; t++) {
#pragma unroll
    for (int k = 0; k < 16; k++) { PIN4(wb[k]); PIN4(wb2[k]); }
    if (t > 0) {
      if (v == 0) POLL_TAGS(TT, t);
      __syncthreads();
      STAGE_DATA(DT, t);
      __syncthreads();
    }
    F4 acc0 = {0.f, 0.f, 0.f, 0.f}, acc1 = {0.f, 0.f, 0.f, 0.f};
    if (t > 0) {
#pragma unroll
      for (int k = 0; k < 16; k++) {
        u32x4 af = lds128[ar * 64 + ((4 * k + q) ^ swz)];
        acc0 = MFMA(af, wb[k], acc0);
        acc1 = MFMA(af, wb2[k], acc1);
      }
    }
#pragma unroll
    for (int r = 0; r < 4; r++) {
      gl[gg][r0v + r][cb0 + ar] = acc0[r];
      gl[gg][r0v + r][cb0 + 16 + ar] = acc1[r];
    }
    __syncthreads();

    float hv0, hv1;
    if (t < len) {
      int cc = 2 * c2;
      float i0 = sigm(gl[0][row][cc] + zr[0][0]);
      float f0 = sigm(gl[1][row][cc] + zr[1][0]);
      float g0 = tanh_(gl[2][row][cc] + zr[2][0]);
      float o0 = sigm(gl[3][row][cc] + zr[3][0]);
      cst0 = f0 * cst0 + i0 * g0;
      hv0 = o0 * tanh_(cst0);
      float i1 = sigm(gl[0][row][cc + 1] + zr[0][1]);
      float f1 = sigm(gl[1][row][cc + 1] + zr[1][1]);
      float g1 = tanh_(gl[2][row][cc + 1] + zr[2][1]);
      float o1 = sigm(gl[3][row][cc + 1] + zr[3][1]);
      cst1 = f1 * cst1 + i1 * g1;
      hv1 = o1 * tanh_(cst1);
    } else {
      hv0 = hr0; hv1 = hr1;
    }
    hr0 = hv0; hr1 = hv1;
    PUBLISH(DT, TT, hv0, hv1, t);

    // out column t-1 (lds128 holds y_{t-1}); off critical path, after tag post.
    // lds128 reuse is safe: next stage happens after the next poll barrier.
    if (t > 0 && (((t - 1) & 1) == (j >> 2)) && v == (((t - 1) >> 1) & 7))
      OUT_PROJ(t - 1);
  }

  // tail: column 511 (parity 1 -> WGs j>=4), v_sel = (511>>1)&7 = 7
  if (j >= 4) {
    if (v == 0) POLL_TAGS(TT, NT);
    __syncthreads();
    STAGE_DATA(DT, NT);
    __syncthreads();
    if (v == 7) OUT_PROJ(NT - 1);
  }
}

// ------------------------- host -------------------------
extern "C" void kernel_launch(void* const* d_in, const int* in_sizes, int n_in,
                              void* d_out, int out_size, void* d_ws, size_t ws_size,
                              hipStream_t stream) {
  const float* x      = (const float*)d_in[0];
  const int* lengths  = (const int*)d_in[1];
  const float* W_ih_e = (const float*)d_in[2];
  const float* W_hh_e = (const float*)d_in[3];
  const float* b_e    = (const float*)d_in[4];
  const float* W_lat  = (const float*)d_in[5];
  const float* b_lat  = (const float*)d_in[6];
  const float* W_ih_d = (const float*)d_in[7];
  const float* W_hh_d = (const float*)d_in[8];
  const float* b_d    = (const float*)d_in[9];
  const float* W_out  = (const float*)d_in[10];
  const float* b_out  = (const float*)d_in[11];
  float* out = (float*)d_out;
  char* ws = (char*)d_ws;

  half8* WfE = (half8*)(ws + OFF_WFE);
  half8* WfD = (half8*)(ws + OFF_WFD);
  half8* WfX = (half8*)(ws + OFF_WFX);
  half8* WfO = (half8*)(ws + OFF_WFO);
  half8* Xf  = (half8*)(ws + OFF_XF);
  u64* DataE = (u64*)(ws + OFF_DE);
  u64* DataD = (u64*)(ws + OFF_DD);
  u32* TagE  = (u32*)(ws + OFF_TE);
  u32* TagD  = (u32*)(ws + OFF_TD);
  float* Z  = (float*)(ws + OFF_Z);
  float* ZX = (float*)(ws + OFF_ZX);

  hipMemsetAsync(TagE, 0, 128u << 10, stream);  // TagE + TagD (contiguous)
  setup_kernel<<<3152, 256, 0, stream>>>(x, W_hh_e, W_ih_e, W_hh_d, W_out,
                                         WfE, WfX, WfD, WfO, Xf);

  enc_persist<<<64, 512, 0, stream>>>((const uint4*)WfE, (const uint4*)WfX,
                                      (const uint4*)Xf, DataE, TagE, b_e, lengths);
  z_kernel<<<128, 256, 0, stream>>>((const u32*)DataE, W_lat, b_lat, Z);
  zx_kernel<<<1024, 256, 0, stream>>>(Z, W_ih_d, b_d, ZX);
  dec_persist<<<64, 512, 0, stream>>>((const uint4*)WfD, (const uint4*)WfO,
                                      DataD, TagD, ZX, b_out, out, lengths);
}